// Round 10
// baseline (111.249 us; speedup 1.0000x reference)
//
#include <hip/hip_runtime.h>

#define N 4096
#define F 512
#define FP 64
#define K 8
#define KFP 512          // K*FP
#define LOG2E 1.44269504088896f

typedef __attribute__((ext_vector_type(8))) short short8;
typedef __attribute__((ext_vector_type(4))) float f32x4;
typedef __attribute__((ext_vector_type(2))) float f32x2;

__device__ __forceinline__ unsigned short f2bs(float x) {
  union { __bf16 b; unsigned short u; } u;
  u.b = (__bf16)x;
  return u.u;
}

#if __has_builtin(__builtin_amdgcn_exp2f)
#define EXP2(x) __builtin_amdgcn_exp2f(x)
#else
#define EXP2(x) __expf((x) * 0.6931471805599453f)
#endif

__device__ __forceinline__ f32x2 pk_add(f32x2 a, f32x2 b) {
  f32x2 d;
  asm("v_pk_add_f32 %0, %1, %2" : "=v"(d) : "v"(a), "v"(b));
  return d;
}
__device__ __forceinline__ f32x2 pk_mul(f32x2 a, f32x2 b) {
  f32x2 d;
  asm("v_pk_mul_f32 %0, %1, %2" : "=v"(d) : "v"(a), "v"(b));
  return d;
}

// masked = bit(off) of mb ? w : 0.0f   (sbfe-sext + and)
__device__ __forceinline__ float mask_w(float w, unsigned mb, int off) {
  return __int_as_float(__float_as_int(w) & __builtin_amdgcn_sbfe((int)mb, off, 1));
}

#define GLOAD_LDS(src, dst) \
  __builtin_amdgcn_global_load_lds( \
      (const __attribute__((address_space(1))) void*)(src), \
      (__attribute__((address_space(3))) void*)(dst), 16, 0, 0)

// ---------------- prep: Xb = bf16(X), Wt = bf16(W transposed) ----------------------------
__global__ __launch_bounds__(256) void prep_fused(const float* __restrict__ X,
                                                  unsigned short* __restrict__ Xb,
                                                  const float* __restrict__ W,
                                                  unsigned short* __restrict__ Wt) {
  __shared__ unsigned short WT16[64][66];
  const int t = threadIdx.x;
  if (blockIdx.x < 1024) {                  // X -> Xb, 8 elems/thread
    const int idx = (blockIdx.x * 256 + t) * 8;
    const float4 v0 = *reinterpret_cast<const float4*>(&X[idx]);
    const float4 v1 = *reinterpret_cast<const float4*>(&X[idx + 4]);
    unsigned short o[8] = {f2bs(v0.x), f2bs(v0.y), f2bs(v0.z), f2bs(v0.w),
                           f2bs(v1.x), f2bs(v1.y), f2bs(v1.z), f2bs(v1.w)};
    *reinterpret_cast<uint4*>(&Xb[idx]) = *reinterpret_cast<uint4*>(&o[0]);
    return;
  }
  const int bid = blockIdx.x - 1024;        // W[K][F][FP] -> Wt[K*FP][F]
  const int k = bid >> 3;
  const int f0 = (bid & 7) * 64;
#pragma unroll
  for (int j = 0; j < 16; j++) {
    const int idx = j * 256 + t;
    const int fl = idx >> 6, p = idx & 63;
    WT16[p][fl] = f2bs(W[(k * F + f0 + fl) * FP + p]);
  }
  __syncthreads();
  const int p = t >> 2, uc = t & 3;
  unsigned short tmp[16];
#pragma unroll
  for (int j = 0; j < 16; j++) tmp[j] = WT16[p][uc * 16 + j];
  unsigned short* dst = &Wt[(k * 64 + p) * F + f0 + uc * 16];
  *reinterpret_cast<uint4*>(dst)     = *reinterpret_cast<uint4*>(&tmp[0]);
  *reinterpret_cast<uint4*>(dst + 8) = *reinterpret_cast<uint4*>(&tmp[8]);
}

// ---------------- kernel A: h_bT = Wt·Xb^T via MFMA + fused f1/f2 + fused adj bits -------
__global__ __launch_bounds__(256, 2) void gemm_h(
    const unsigned short* __restrict__ Xb, const unsigned short* __restrict__ Wt,
    const float* __restrict__ a, unsigned short* __restrict__ h_bT,
    float* __restrict__ f1, float* __restrict__ f2,
    const int* __restrict__ adj, unsigned long long* __restrict__ adjb) {
  __shared__ __align__(16) unsigned char AT[2][8192];   // Wt tile [64c][8u][16B]
  __shared__ __align__(16) unsigned char BT[2][8192];   // Xb tile [64n][8u][16B]
  __shared__ float F1L[2][64], F2L[2][64];

  const int t = threadIdx.x;
  const int k = blockIdx.x & 7;
  const int n0 = (blockIdx.x >> 3) * 64;
  const int wave = t >> 6, lane = t & 63;
  const int cg = wave >> 1, ng = wave & 1;
  const int col = lane & 15, kg = lane >> 4;
  const unsigned short* __restrict__ Wk = Wt + (size_t)k * 64 * F;

  f32x4 acc[2][2];
#pragma unroll
  for (int i = 0; i < 2; i++)
#pragma unroll
    for (int j = 0; j < 2; j++) acc[i][j] = (f32x4){0.f, 0.f, 0.f, 0.f};

  auto stage = [&](int tt, int buf) {
    const int f0 = tt * 64;
#pragma unroll
    for (int m = 0; m < 2; m++) {
      const int g = wave * 128 + m * 64 + lane;
      const int row = g >> 3, pu = g & 7;
      const int u = pu ^ (row & 7);
      GLOAD_LDS(Wk + (size_t)row * F + f0 + u * 8,
                AT[buf] + (wave * 128 + m * 64) * 16);
      GLOAD_LDS(Xb + (size_t)(n0 + row) * F + f0 + u * 8,
                BT[buf] + (wave * 128 + m * 64) * 16);
    }
  };

  auto compute = [&](int buf) {
#pragma unroll
    for (int ks = 0; ks < 2; ks++) {
      const int u0 = ks * 4 + kg;
      short8 af[2], bf[2];
#pragma unroll
      for (int i = 0; i < 2; i++) {
        const int rowA = cg * 32 + i * 16 + col;
        af[i] = *reinterpret_cast<const short8*>(
            AT[buf] + (rowA * 8 + (u0 ^ (rowA & 7))) * 16);
        const int rowB = ng * 32 + i * 16 + col;
        bf[i] = *reinterpret_cast<const short8*>(
            BT[buf] + (rowB * 8 + (u0 ^ (rowB & 7))) * 16);
      }
#pragma unroll
      for (int i = 0; i < 2; i++)
#pragma unroll
        for (int j = 0; j < 2; j++)
          acc[i][j] = __builtin_amdgcn_mfma_f32_16x16x32_bf16(af[i], bf[j], acc[i][j], 0, 0, 0);
    }
  };

  // fused adjacency: block owns 512 adjb words; wave owns 128; 16 per K-tile.
  int adjv[16];
  const int wb_wave = blockIdx.x * 512 + wave * 128;
  auto adj_load = [&](int c) {
    const int* p = adj + (size_t)(wb_wave + c * 16) * 64 + lane;
#pragma unroll
    for (int x = 0; x < 16; x++) adjv[x] = p[x * 64];
  };
  auto adj_process = [&](int c) {
    unsigned long long ms[16];
#pragma unroll
    for (int x = 0; x < 16; x++) ms[x] = __ballot(adjv[x] > 0);
    if (lane == 0) {
#pragma unroll
      for (int x = 0; x < 16; x++) adjb[wb_wave + c * 16 + x] = ms[x];
    }
  };

  stage(0, 0);
  adj_load(0);
  for (int tt = 0; tt < F / 64; ++tt) {
    const int cur = tt & 1;
    __builtin_amdgcn_s_barrier();
    __builtin_amdgcn_sched_barrier(0);
    if (tt + 1 < F / 64) {
      stage(tt + 1, 1 - cur);
      asm volatile("s_waitcnt vmcnt(4)" ::: "memory");
    } else {
      asm volatile("s_waitcnt vmcnt(0)" ::: "memory");
    }
    __builtin_amdgcn_s_barrier();
    __builtin_amdgcn_sched_barrier(0);
    if (tt >= 1) {
      adj_process(tt - 1);
      adj_load(tt);
    }
    compute(cur);
  }
  asm volatile("s_waitcnt vmcnt(0)" ::: "memory");
  adj_process(7);

  // ---- epilogue: h_bT bf16 stores + fused f1/f2 (pre-scaled by log2e) ----
  float p1[2] = {0.f, 0.f}, p2[2] = {0.f, 0.f};
#pragma unroll
  for (int i = 0; i < 2; i++) {
#pragma unroll
    for (int r = 0; r < 4; r++) {
      const int p = cg * 32 + i * 16 + kg * 4 + r;
      const float as = a[k * 128 + p];
      const float ad = a[k * 128 + 64 + p];
#pragma unroll
      for (int j = 0; j < 2; j++) {
        const float v = acc[i][j][r];
        h_bT[(size_t)(k * 64 + p) * N + n0 + ng * 32 + j * 16 + col] = f2bs(v);
        p1[j] = fmaf(v, as, p1[j]);
        p2[j] = fmaf(v, ad, p2[j]);
      }
    }
  }
#pragma unroll
  for (int j = 0; j < 2; j++) {
    p1[j] += __shfl_xor(p1[j], 16); p1[j] += __shfl_xor(p1[j], 32);
    p2[j] += __shfl_xor(p2[j], 16); p2[j] += __shfl_xor(p2[j], 32);
    if (kg == 0) {
      F1L[cg][ng * 32 + j * 16 + col] = p1[j];
      F2L[cg][ng * 32 + j * 16 + col] = p2[j];
    }
  }
  __syncthreads();
  if (t < 64) {
    f1[k * N + n0 + t] = (F1L[0][t] + F1L[1][t]) * LOG2E;
    f2[k * N + n0 + t] = (F2L[0][t] + F2L[1][t]) * LOG2E;
  }
}

// ---------------- kernel C: barrier-free MFMA masked-softmax attention -------------------
// block = 256 thr = 4 independent waves (one 32-row i-group x 4 j-quarters).
// No per-tile barriers: h fragments / f1 / adjb stream global(L2)->registers.
// LDS used only for the one-shot epilogue cross-jq reduction.
__global__ __launch_bounds__(256, 4) void attn_mfma(
    const unsigned short* __restrict__ h_bT, const float* __restrict__ f1,
    const float* __restrict__ f2, const unsigned long long* __restrict__ adjb,
    float* __restrict__ out) {
  __shared__ float CL[3 * 32 * 66];     // 25.3 KB epilogue exchange
  __shared__ float DL[4][32];

  const int tid = threadIdx.x;
  const int k = blockIdx.x & 7;
  const int i0 = (blockIdx.x >> 3) * 32;
  const int jq = tid >> 6, lane = tid & 63;
  const int col = lane & 15, kg = lane >> 4;

  const float* __restrict__ f1k = f1 + k * N;
  const unsigned short* __restrict__ hk = h_bT + (size_t)k * 64 * N;

  const float f2r0 = f2[k * N + i0 + col];          // pre-scaled by log2e
  const float f2r1 = f2[k * N + i0 + 16 + col];
  const f32x2 f2r0_2 = {f2r0, f2r0};
  const f32x2 f2r1_2 = {f2r1, f2r1};
  const f32x2 c02 = {0.2f, 0.2f};
  const unsigned long long* __restrict__ ar0 = adjb + (size_t)(i0 + col) * 64;
  const unsigned long long* __restrict__ ar1 = adjb + (size_t)(i0 + 16 + col) * 64;

  f32x4 acc[2][4];
  f32x4 accden[2];
#pragma unroll
  for (int a = 0; a < 2; a++) {
    accden[a] = (f32x4){0.f, 0.f, 0.f, 0.f};
#pragma unroll
    for (int n = 0; n < 4; n++) acc[a][n] = (f32x4){0.f, 0.f, 0.f, 0.f};
  }
  short8 bones;
#pragma unroll
  for (int e = 0; e < 8; e++) bones[e] = (short)0x3F80;

  // each wave streams its contiguous j-quarter: 16 groups of 64 j
  for (int jg = 0; jg < 16; ++jg) {
    const int j0 = jq * 1024 + jg * 64;
    const uint2 aw0 = *reinterpret_cast<const uint2*>(ar0 + (j0 >> 6));
    const uint2 aw1 = *reinterpret_cast<const uint2*>(ar1 + (j0 >> 6));
#pragma unroll
    for (int ks = 0; ks < 2; ks++) {
      const int jb = j0 + ks * 32 + kg * 8;
      const float4 fa = *reinterpret_cast<const float4*>(&f1k[jb]);
      const float4 fb = *reinterpret_cast<const float4*>(&f1k[jb + 4]);
      const unsigned m0 = ks ? aw0.y : aw0.x;
      const unsigned m1 = ks ? aw1.y : aw1.x;

      short8 bfrag[4];
#pragma unroll
      for (int n = 0; n < 4; n++)
        bfrag[n] = *reinterpret_cast<const short8*>(
            &hk[(size_t)(n * 16 + col) * N + jb]);

      const f32x2 prs[4] = {{fa.x, fa.y}, {fa.z, fa.w}, {fb.x, fb.y}, {fb.z, fb.w}};
      union { unsigned u[4]; short8 s; } A0, A1;
#pragma unroll
      for (int e2 = 0; e2 < 4; e2++) {
        const f32x2 t0 = pk_add(prs[e2], f2r0_2);
        const f32x2 t1 = pk_add(prs[e2], f2r1_2);
        const f32x2 u0 = pk_mul(t0, c02);
        const f32x2 u1 = pk_mul(t1, c02);
        float w0a = EXP2(fmaxf(t0.x, u0.x));
        float w0b = EXP2(fmaxf(t0.y, u0.y));
        float w1a = EXP2(fmaxf(t1.x, u1.x));
        float w1b = EXP2(fmaxf(t1.y, u1.y));
        const int ob = kg * 8 + 2 * e2;
        w0a = mask_w(w0a, m0, ob);     w0b = mask_w(w0b, m0, ob + 1);
        w1a = mask_w(w1a, m1, ob);     w1b = mask_w(w1b, m1, ob + 1);
        asm("v_cvt_pk_bf16_f32 %0, %1, %2" : "=v"(A0.u[e2]) : "v"(w0a), "v"(w0b));
        asm("v_cvt_pk_bf16_f32 %0, %1, %2" : "=v"(A1.u[e2]) : "v"(w1a), "v"(w1b));
      }

      __builtin_amdgcn_s_setprio(1);
      accden[0] = __builtin_amdgcn_mfma_f32_16x16x32_bf16(A0.s, bones, accden[0], 0, 0, 0);
      accden[1] = __builtin_amdgcn_mfma_f32_16x16x32_bf16(A1.s, bones, accden[1], 0, 0, 0);
#pragma unroll
      for (int n = 0; n < 4; n++) {
        acc[0][n] = __builtin_amdgcn_mfma_f32_16x16x32_bf16(A0.s, bfrag[n], acc[0][n], 0, 0, 0);
        acc[1][n] = __builtin_amdgcn_mfma_f32_16x16x32_bf16(A1.s, bfrag[n], acc[1][n], 0, 0, 0);
      }
      __builtin_amdgcn_s_setprio(0);
    }
  }

  // ---- one-shot epilogue: cross-jq reduction + normalize + store ----
  if (col == 0) {
#pragma unroll
    for (int a = 0; a < 2; a++)
#pragma unroll
      for (int r = 0; r < 4; r++) DL[jq][a * 16 + kg * 4 + r] = accden[a][r];
  }
  if (jq != 0) {
#pragma unroll
    for (int a = 0; a < 2; a++)
#pragma unroll
      for (int n = 0; n < 4; n++)
#pragma unroll
        for (int r = 0; r < 4; r++)
          CL[((jq - 1) * 32 + a * 16 + kg * 4 + r) * 66 + n * 16 + col] = acc[a][n][r];
  }
  __syncthreads();
  if (jq == 0) {
#pragma unroll
    for (int a = 0; a < 2; a++) {
#pragma unroll
      for (int r = 0; r < 4; r++) {
        const int il = a * 16 + kg * 4 + r;
        const float den = DL[0][il] + DL[1][il] + DL[2][il] + DL[3][il];
        const float rinv = 1.f / den;
#pragma unroll
        for (int n = 0; n < 4; n++) {
          float v = acc[a][n][r];
          v += CL[(0 * 32 + il) * 66 + n * 16 + col];
          v += CL[(1 * 32 + il) * 66 + n * 16 + col];
          v += CL[(2 * 32 + il) * 66 + n * 16 + col];
          out[(size_t)(i0 + il) * KFP + k * 64 + n * 16 + col] = v * rinv;
        }
      }
    }
  }
}

// ---------------- launch ----------------------------------------------------------------
extern "C" void kernel_launch(void* const* d_in, const int* in_sizes, int n_in,
                              void* d_out, int out_size, void* d_ws, size_t ws_size,
                              hipStream_t stream) {
  const float* X   = (const float*)d_in[0];             // (N, F)
  const int*   adj = (const int*)d_in[1];               // (N, N)
  const float* W   = (const float*)d_in[2];             // (K, F, FP)
  const float* a   = (const float*)d_in[3];             // (K, 2*FP, 1)
  float* out = (float*)d_out;                           // (N, K*FP) = 8 MB

  char* ws = (char*)d_ws;
  unsigned short* h_bT = (unsigned short*)(ws);                    // 4 MB
  float* f1  = (float*)(ws + 4194304);                             // 128 KB
  float* f2  = (float*)(ws + 4325376);                             // 128 KB
  unsigned long long* adjb = (unsigned long long*)(ws + 4456448);  // 2 MB
  unsigned short* Wt = (unsigned short*)(ws + 6553600);            // 512 KB
  // Xb parked in d_out (4 MB of its 8 MB) — consumed by gemm_h before attn overwrites out
  unsigned short* Xb = (unsigned short*)d_out;

  hipLaunchKernelGGL(prep_fused, dim3(1024 + K * (F / 64)), dim3(256), 0, stream,
                     X, Xb, W, Wt);
  hipLaunchKernelGGL(gemm_h, dim3(K * (N / 64)), dim3(256), 0, stream,
                     Xb, Wt, a, h_bT, f1, f2, adj, adjb);
  hipLaunchKernelGGL(attn_mfma, dim3((N / 32) * K), dim3(256), 0, stream,
                     h_bT, f1, f2, adjb, out);
}

// Round 11
// 83.018 us; speedup vs baseline: 1.3401x; 1.3401x over previous
//
#include <hip/hip_runtime.h>

#define N 4096
#define F 512
#define FP 64
#define K 8
#define KFP 512          // K*FP
#define LOG2E 1.44269504088896f

typedef __attribute__((ext_vector_type(8))) short short8;
typedef __attribute__((ext_vector_type(4))) float f32x4;
typedef __attribute__((ext_vector_type(2))) float f32x2;

__device__ __forceinline__ unsigned short f2bs(float x) {
  union { __bf16 b; unsigned short u; } u;
  u.b = (__bf16)x;
  return u.u;
}

#if __has_builtin(__builtin_amdgcn_exp2f)
#define EXP2(x) __builtin_amdgcn_exp2f(x)
#else
#define EXP2(x) __expf((x) * 0.6931471805599453f)
#endif

__device__ __forceinline__ f32x2 pk_add(f32x2 a, f32x2 b) {
  f32x2 d;
  asm("v_pk_add_f32 %0, %1, %2" : "=v"(d) : "v"(a), "v"(b));
  return d;
}
__device__ __forceinline__ f32x2 pk_mul(f32x2 a, f32x2 b) {
  f32x2 d;
  asm("v_pk_mul_f32 %0, %1, %2" : "=v"(d) : "v"(a), "v"(b));
  return d;
}

// masked = bit(off) of mb ? w : 0.0f   (sbfe-sext + and)
__device__ __forceinline__ float mask_w(float w, unsigned mb, int off) {
  return __int_as_float(__float_as_int(w) & __builtin_amdgcn_sbfe((int)mb, off, 1));
}

#define GLOAD_LDS(src, dst) \
  __builtin_amdgcn_global_load_lds( \
      (const __attribute__((address_space(1))) void*)(src), \
      (__attribute__((address_space(3))) void*)(dst), 16, 0, 0)

// ---------------- prep: Xb = bf16(X), Wt = bf16(W transposed) ----------------------------
__global__ __launch_bounds__(256) void prep_fused(const float* __restrict__ X,
                                                  unsigned short* __restrict__ Xb,
                                                  const float* __restrict__ W,
                                                  unsigned short* __restrict__ Wt) {
  __shared__ unsigned short WT16[64][66];
  const int t = threadIdx.x;
  if (blockIdx.x < 1024) {                  // X -> Xb, 8 elems/thread
    const int idx = (blockIdx.x * 256 + t) * 8;
    const float4 v0 = *reinterpret_cast<const float4*>(&X[idx]);
    const float4 v1 = *reinterpret_cast<const float4*>(&X[idx + 4]);
    unsigned short o[8] = {f2bs(v0.x), f2bs(v0.y), f2bs(v0.z), f2bs(v0.w),
                           f2bs(v1.x), f2bs(v1.y), f2bs(v1.z), f2bs(v1.w)};
    *reinterpret_cast<uint4*>(&Xb[idx]) = *reinterpret_cast<uint4*>(&o[0]);
    return;
  }
  const int bid = blockIdx.x - 1024;        // W[K][F][FP] -> Wt[K*FP][F]
  const int k = bid >> 3;
  const int f0 = (bid & 7) * 64;
#pragma unroll
  for (int j = 0; j < 16; j++) {
    const int idx = j * 256 + t;
    const int fl = idx >> 6, p = idx & 63;
    WT16[p][fl] = f2bs(W[(k * F + f0 + fl) * FP + p]);
  }
  __syncthreads();
  const int p = t >> 2, uc = t & 3;
  unsigned short tmp[16];
#pragma unroll
  for (int j = 0; j < 16; j++) tmp[j] = WT16[p][uc * 16 + j];
  unsigned short* dst = &Wt[(k * 64 + p) * F + f0 + uc * 16];
  *reinterpret_cast<uint4*>(dst)     = *reinterpret_cast<uint4*>(&tmp[0]);
  *reinterpret_cast<uint4*>(dst + 8) = *reinterpret_cast<uint4*>(&tmp[8]);
}

// ---------------- kernel A: h_bT = Wt·Xb^T via MFMA + fused f1/f2 + fused adj bits -------
__global__ __launch_bounds__(256, 2) void gemm_h(
    const unsigned short* __restrict__ Xb, const unsigned short* __restrict__ Wt,
    const float* __restrict__ a, unsigned short* __restrict__ h_bT,
    float* __restrict__ f1, float* __restrict__ f2,
    const int* __restrict__ adj, unsigned long long* __restrict__ adjb) {
  __shared__ __align__(16) unsigned char AT[2][8192];   // Wt tile [64c][8u][16B]
  __shared__ __align__(16) unsigned char BT[2][8192];   // Xb tile [64n][8u][16B]
  __shared__ float F1L[2][64], F2L[2][64];

  const int t = threadIdx.x;
  const int k = blockIdx.x & 7;
  const int n0 = (blockIdx.x >> 3) * 64;
  const int wave = t >> 6, lane = t & 63;
  const int cg = wave >> 1, ng = wave & 1;
  const int col = lane & 15, kg = lane >> 4;
  const unsigned short* __restrict__ Wk = Wt + (size_t)k * 64 * F;

  f32x4 acc[2][2];
#pragma unroll
  for (int i = 0; i < 2; i++)
#pragma unroll
    for (int j = 0; j < 2; j++) acc[i][j] = (f32x4){0.f, 0.f, 0.f, 0.f};

  auto stage = [&](int tt, int buf) {
    const int f0 = tt * 64;
#pragma unroll
    for (int m = 0; m < 2; m++) {
      const int g = wave * 128 + m * 64 + lane;
      const int row = g >> 3, pu = g & 7;
      const int u = pu ^ (row & 7);
      GLOAD_LDS(Wk + (size_t)row * F + f0 + u * 8,
                AT[buf] + (wave * 128 + m * 64) * 16);
      GLOAD_LDS(Xb + (size_t)(n0 + row) * F + f0 + u * 8,
                BT[buf] + (wave * 128 + m * 64) * 16);
    }
  };

  auto compute = [&](int buf) {
#pragma unroll
    for (int ks = 0; ks < 2; ks++) {
      const int u0 = ks * 4 + kg;
      short8 af[2], bf[2];
#pragma unroll
      for (int i = 0; i < 2; i++) {
        const int rowA = cg * 32 + i * 16 + col;
        af[i] = *reinterpret_cast<const short8*>(
            AT[buf] + (rowA * 8 + (u0 ^ (rowA & 7))) * 16);
        const int rowB = ng * 32 + i * 16 + col;
        bf[i] = *reinterpret_cast<const short8*>(
            BT[buf] + (rowB * 8 + (u0 ^ (rowB & 7))) * 16);
      }
#pragma unroll
      for (int i = 0; i < 2; i++)
#pragma unroll
        for (int j = 0; j < 2; j++)
          acc[i][j] = __builtin_amdgcn_mfma_f32_16x16x32_bf16(af[i], bf[j], acc[i][j], 0, 0, 0);
    }
  };

  // fused adjacency: block owns 512 adjb words; wave owns 128; 16 per K-tile.
  int adjv[16];
  const int wb_wave = blockIdx.x * 512 + wave * 128;
  auto adj_load = [&](int c) {
    const int* p = adj + (size_t)(wb_wave + c * 16) * 64 + lane;
#pragma unroll
    for (int x = 0; x < 16; x++) adjv[x] = p[x * 64];
  };
  auto adj_process = [&](int c) {
    unsigned long long ms[16];
#pragma unroll
    for (int x = 0; x < 16; x++) ms[x] = __ballot(adjv[x] > 0);
    if (lane == 0) {
#pragma unroll
      for (int x = 0; x < 16; x++) adjb[wb_wave + c * 16 + x] = ms[x];
    }
  };

  stage(0, 0);
  adj_load(0);
  for (int tt = 0; tt < F / 64; ++tt) {
    const int cur = tt & 1;
    __builtin_amdgcn_s_barrier();
    __builtin_amdgcn_sched_barrier(0);
    if (tt + 1 < F / 64) {
      stage(tt + 1, 1 - cur);
      asm volatile("s_waitcnt vmcnt(4)" ::: "memory");
    } else {
      asm volatile("s_waitcnt vmcnt(0)" ::: "memory");
    }
    __builtin_amdgcn_s_barrier();
    __builtin_amdgcn_sched_barrier(0);
    if (tt >= 1) {
      adj_process(tt - 1);
      adj_load(tt);
    }
    compute(cur);
  }
  asm volatile("s_waitcnt vmcnt(0)" ::: "memory");
  adj_process(7);

  // ---- epilogue: h_bT bf16 stores + fused f1/f2 (pre-scaled by log2e) ----
  float p1[2] = {0.f, 0.f}, p2[2] = {0.f, 0.f};
#pragma unroll
  for (int i = 0; i < 2; i++) {
#pragma unroll
    for (int r = 0; r < 4; r++) {
      const int p = cg * 32 + i * 16 + kg * 4 + r;
      const float as = a[k * 128 + p];
      const float ad = a[k * 128 + 64 + p];
#pragma unroll
      for (int j = 0; j < 2; j++) {
        const float v = acc[i][j][r];
        h_bT[(size_t)(k * 64 + p) * N + n0 + ng * 32 + j * 16 + col] = f2bs(v);
        p1[j] = fmaf(v, as, p1[j]);
        p2[j] = fmaf(v, ad, p2[j]);
      }
    }
  }
#pragma unroll
  for (int j = 0; j < 2; j++) {
    p1[j] += __shfl_xor(p1[j], 16); p1[j] += __shfl_xor(p1[j], 32);
    p2[j] += __shfl_xor(p2[j], 16); p2[j] += __shfl_xor(p2[j], 32);
    if (kg == 0) {
      F1L[cg][ng * 32 + j * 16 + col] = p1[j];
      F2L[cg][ng * 32 + j * 16 + col] = p2[j];
    }
  }
  __syncthreads();
  if (t < 64) {
    f1[k * N + n0 + t] = (F1L[0][t] + F1L[1][t]) * LOG2E;
    f2[k * N + n0 + t] = (F2L[0][t] + F2L[1][t]) * LOG2E;
  }
}

// ---------------- kernel C: barrier-free per-wave LDS-staged attention -------------------
// block = 256 thr = 4 waves (32 i-rows x 4 j-quarters), 1024 blocks = 4/CU.
// Each wave owns a PRIVATE 8KB LDS slice, stages its own next tile via global_load_lds,
// self-syncs with vmcnt/lgkmcnt. No block barriers until the epilogue.
__global__ __launch_bounds__(256, 4) void attn_mfma(
    const unsigned short* __restrict__ h_bT, const float* __restrict__ f1,
    const float* __restrict__ f2, const unsigned long long* __restrict__ adjb,
    float* __restrict__ out) {
  __shared__ __align__(16) unsigned char SMEM[32768];   // 4 x 8KB slices; CL aliased at end
  __shared__ float DL[4][32];

  const int tid = threadIdx.x;
  const int k = blockIdx.x & 7;
  const int i0 = (blockIdx.x >> 3) * 32;
  const int jq = tid >> 6, lane = tid & 63;
  const int col = lane & 15, kg = lane >> 4;

  const float* __restrict__ f1k = f1 + k * N;
  const unsigned char* __restrict__ hbb =
      (const unsigned char*)(h_bT + (size_t)k * 64 * N);

  const float f2r0 = f2[k * N + i0 + col];          // pre-scaled by log2e
  const float f2r1 = f2[k * N + i0 + 16 + col];
  const f32x2 f2r0_2 = {f2r0, f2r0};
  const f32x2 f2r1_2 = {f2r1, f2r1};
  const f32x2 c02 = {0.2f, 0.2f};
  const unsigned long long* __restrict__ ar0 = adjb + (size_t)(i0 + col) * 64;
  const unsigned long long* __restrict__ ar1 = adjb + (size_t)(i0 + 16 + col) * 64;

  f32x4 acc[2][4];
  f32x4 accden[2];
#pragma unroll
  for (int a = 0; a < 2; a++) {
    accden[a] = (f32x4){0.f, 0.f, 0.f, 0.f};
#pragma unroll
    for (int n = 0; n < 4; n++) acc[a][n] = (f32x4){0.f, 0.f, 0.f, 0.f};
  }
  short8 bones;
#pragma unroll
  for (int e = 0; e < 8; e++) bones[e] = (short)0x3F80;

  // wave's private slice: [64 rows][8 chunks of 16B], swizzle chunk u -> u^(row&7)
  unsigned char* MY = SMEM + jq * 8192;
  const int jqbase = jq * 1024;                     // this wave's j-quarter start

  auto stage = [&](int jg) {
#pragma unroll
    for (int m = 0; m < 8; m++) {
      const int row = m * 8 + (lane >> 3);
      const int phys = lane & 7;
      const int u = phys ^ (row & 7);
      GLOAD_LDS(hbb + (size_t)row * (N * 2) + (jqbase + jg * 64 + u * 8) * 2,
                MY + m * 1024);
    }
  };

  stage(0);
  for (int jg = 0; jg < 16; ++jg) {
    // ---- small operands direct from L2 (latency covered by other waves) ----
    const uint2 aw0 = *reinterpret_cast<const uint2*>(ar0 + jq * 16 + jg);
    const uint2 aw1 = *reinterpret_cast<const uint2*>(ar1 + jq * 16 + jg);

    // ---- score math for both ks halves (independent of h staging) ----
    short8 Af0[2], Af1[2];
#pragma unroll
    for (int ks = 0; ks < 2; ks++) {
      const int jb = jqbase + jg * 64 + ks * 32 + kg * 8;
      const float4 fa = *reinterpret_cast<const float4*>(&f1k[jb]);
      const float4 fb = *reinterpret_cast<const float4*>(&f1k[jb + 4]);
      const unsigned m0 = ks ? aw0.y : aw0.x;
      const unsigned m1 = ks ? aw1.y : aw1.x;
      const f32x2 prs[4] = {{fa.x, fa.y}, {fa.z, fa.w}, {fb.x, fb.y}, {fb.z, fb.w}};
      union { unsigned u[4]; short8 s; } A0, A1;
#pragma unroll
      for (int e2 = 0; e2 < 4; e2++) {
        const f32x2 t0 = pk_add(prs[e2], f2r0_2);
        const f32x2 t1 = pk_add(prs[e2], f2r1_2);
        const f32x2 u0 = pk_mul(t0, c02);
        const f32x2 u1 = pk_mul(t1, c02);
        float w0a = EXP2(fmaxf(t0.x, u0.x));
        float w0b = EXP2(fmaxf(t0.y, u0.y));
        float w1a = EXP2(fmaxf(t1.x, u1.x));
        float w1b = EXP2(fmaxf(t1.y, u1.y));
        const int ob = kg * 8 + 2 * e2;
        w0a = mask_w(w0a, m0, ob);     w0b = mask_w(w0b, m0, ob + 1);
        w1a = mask_w(w1a, m1, ob);     w1b = mask_w(w1b, m1, ob + 1);
        asm("v_cvt_pk_bf16_f32 %0, %1, %2" : "=v"(A0.u[e2]) : "v"(w0a), "v"(w0b));
        asm("v_cvt_pk_bf16_f32 %0, %1, %2" : "=v"(A1.u[e2]) : "v"(w1a), "v"(w1b));
      }
      Af0[ks] = A0.s;
      Af1[ks] = A1.s;
    }

    // ---- stage(jg) landed long ago (hidden under score math) ----
    asm volatile("s_waitcnt vmcnt(0)" ::: "memory");
    __builtin_amdgcn_sched_barrier(0);
    short8 bfr[2][4];
#pragma unroll
    for (int ks = 0; ks < 2; ks++)
#pragma unroll
      for (int n = 0; n < 4; n++) {
        const int row_b = n * 16 + col;
        const int u = ks * 4 + kg;
        bfr[ks][n] = *reinterpret_cast<const short8*>(
            MY + row_b * 128 + (u ^ (row_b & 7)) * 16);
      }
    asm volatile("s_waitcnt lgkmcnt(0)" ::: "memory");
    __builtin_amdgcn_sched_barrier(0);
    if (jg + 1 < 16) stage(jg + 1);       // safe: reads retired; writes land later

    __builtin_amdgcn_s_setprio(1);
#pragma unroll
    for (int ks = 0; ks < 2; ks++) {
      accden[0] = __builtin_amdgcn_mfma_f32_16x16x32_bf16(Af0[ks], bones, accden[0], 0, 0, 0);
      accden[1] = __builtin_amdgcn_mfma_f32_16x16x32_bf16(Af1[ks], bones, accden[1], 0, 0, 0);
#pragma unroll
      for (int n = 0; n < 4; n++) {
        acc[0][n] = __builtin_amdgcn_mfma_f32_16x16x32_bf16(Af0[ks], bfr[ks][n], acc[0][n], 0, 0, 0);
        acc[1][n] = __builtin_amdgcn_mfma_f32_16x16x32_bf16(Af1[ks], bfr[ks][n], acc[1][n], 0, 0, 0);
      }
    }
    __builtin_amdgcn_s_setprio(0);
  }

  __syncthreads();                         // all waves done; SMEM reusable as CL

  // ---- one-shot epilogue: cross-jq reduction + normalize + store ----
  float* CL = (float*)SMEM;                // 3*32*66*4 = 25.3KB <= 32KB
  if (col == 0) {
#pragma unroll
    for (int a = 0; a < 2; a++)
#pragma unroll
      for (int r = 0; r < 4; r++) DL[jq][a * 16 + kg * 4 + r] = accden[a][r];
  }
  if (jq != 0) {
#pragma unroll
    for (int a = 0; a < 2; a++)
#pragma unroll
      for (int n = 0; n < 4; n++)
#pragma unroll
        for (int r = 0; r < 4; r++)
          CL[((jq - 1) * 32 + a * 16 + kg * 4 + r) * 66 + n * 16 + col] = acc[a][n][r];
  }
  __syncthreads();
  if (jq == 0) {
#pragma unroll
    for (int a = 0; a < 2; a++) {
#pragma unroll
      for (int r = 0; r < 4; r++) {
        const int il = a * 16 + kg * 4 + r;
        const float den = DL[0][il] + DL[1][il] + DL[2][il] + DL[3][il];
        const float rinv = 1.f / den;
#pragma unroll
        for (int n = 0; n < 4; n++) {
          float v = acc[a][n][r];
          v += CL[(0 * 32 + il) * 66 + n * 16 + col];
          v += CL[(1 * 32 + il) * 66 + n * 16 + col];
          v += CL[(2 * 32 + il) * 66 + n * 16 + col];
          out[(size_t)(i0 + il) * KFP + k * 64 + n * 16 + col] = v * rinv;
        }
      }
    }
  }
}

// ---------------- launch ----------------------------------------------------------------
extern "C" void kernel_launch(void* const* d_in, const int* in_sizes, int n_in,
                              void* d_out, int out_size, void* d_ws, size_t ws_size,
                              hipStream_t stream) {
  const float* X   = (const float*)d_in[0];             // (N, F)
  const int*   adj = (const int*)d_in[1];               // (N, N)
  const float* W   = (const float*)d_in[2];             // (K, F, FP)
  const float* a   = (const float*)d_in[3];             // (K, 2*FP, 1)
  float* out = (float*)d_out;                           // (N, K*FP) = 8 MB

  char* ws = (char*)d_ws;
  unsigned short* h_bT = (unsigned short*)(ws);                    // 4 MB
  float* f1  = (float*)(ws + 4194304);                             // 128 KB
  float* f2  = (float*)(ws + 4325376);                             // 128 KB
  unsigned long long* adjb = (unsigned long long*)(ws + 4456448);  // 2 MB
  unsigned short* Wt = (unsigned short*)(ws + 6553600);            // 512 KB
  // Xb parked in d_out (4 MB of its 8 MB) — consumed by gemm_h before attn overwrites out
  unsigned short* Xb = (unsigned short*)d_out;

  hipLaunchKernelGGL(prep_fused, dim3(1024 + K * (F / 64)), dim3(256), 0, stream,
                     X, Xb, W, Wt);
  hipLaunchKernelGGL(gemm_h, dim3(K * (N / 64)), dim3(256), 0, stream,
                     Xb, Wt, a, h_bT, f1, f2, adj, adjb);
  hipLaunchKernelGGL(attn_mfma, dim3((N / 32) * K), dim3(256), 0, stream,
                     h_bT, f1, f2, adjb, out);
}

// Round 12
// 79.430 us; speedup vs baseline: 1.4006x; 1.0452x over previous
//
#include <hip/hip_runtime.h>

#define N 4096
#define F 512
#define FP 64
#define K 8
#define KFP 512          // K*FP
#define LOG2E 1.44269504088896f

typedef __attribute__((ext_vector_type(8))) short short8;
typedef __attribute__((ext_vector_type(4))) float f32x4;
typedef __attribute__((ext_vector_type(2))) float f32x2;

__device__ __forceinline__ unsigned short f2bs(float x) {
  union { __bf16 b; unsigned short u; } u;
  u.b = (__bf16)x;
  return u.u;
}

// guaranteed single-instruction exp2
__device__ __forceinline__ float exp2_asm(float x) {
  float d;
  asm("v_exp_f32 %0, %1" : "=v"(d) : "v"(x));
  return d;
}

__device__ __forceinline__ f32x2 pk_add(f32x2 a, f32x2 b) {
  f32x2 d;
  asm("v_pk_add_f32 %0, %1, %2" : "=v"(d) : "v"(a), "v"(b));
  return d;
}
__device__ __forceinline__ f32x2 pk_mul(f32x2 a, f32x2 b) {
  f32x2 d;
  asm("v_pk_mul_f32 %0, %1, %2" : "=v"(d) : "v"(a), "v"(b));
  return d;
}

// masked = bit(off) of mb ? w : 0.0f   (sbfe-sext + and)
__device__ __forceinline__ float mask_w(float w, unsigned mb, int off) {
  return __int_as_float(__float_as_int(w) & __builtin_amdgcn_sbfe((int)mb, off, 1));
}

#define GLOAD_LDS(src, dst) \
  __builtin_amdgcn_global_load_lds( \
      (const __attribute__((address_space(1))) void*)(src), \
      (__attribute__((address_space(3))) void*)(dst), 16, 0, 0)

// ---------------- prep: Xb = bf16(X), Wt = bf16(W transposed) ----------------------------
__global__ __launch_bounds__(256) void prep_fused(const float* __restrict__ X,
                                                  unsigned short* __restrict__ Xb,
                                                  const float* __restrict__ W,
                                                  unsigned short* __restrict__ Wt) {
  __shared__ unsigned short WT16[64][66];
  const int t = threadIdx.x;
  if (blockIdx.x < 1024) {                  // X -> Xb, 8 elems/thread
    const int idx = (blockIdx.x * 256 + t) * 8;
    const float4 v0 = *reinterpret_cast<const float4*>(&X[idx]);
    const float4 v1 = *reinterpret_cast<const float4*>(&X[idx + 4]);
    unsigned short o[8] = {f2bs(v0.x), f2bs(v0.y), f2bs(v0.z), f2bs(v0.w),
                           f2bs(v1.x), f2bs(v1.y), f2bs(v1.z), f2bs(v1.w)};
    *reinterpret_cast<uint4*>(&Xb[idx]) = *reinterpret_cast<uint4*>(&o[0]);
    return;
  }
  const int bid = blockIdx.x - 1024;        // W[K][F][FP] -> Wt[K*FP][F]
  const int k = bid >> 3;
  const int f0 = (bid & 7) * 64;
#pragma unroll
  for (int j = 0; j < 16; j++) {
    const int idx = j * 256 + t;
    const int fl = idx >> 6, p = idx & 63;
    WT16[p][fl] = f2bs(W[(k * F + f0 + fl) * FP + p]);
  }
  __syncthreads();
  const int p = t >> 2, uc = t & 3;
  unsigned short tmp[16];
#pragma unroll
  for (int j = 0; j < 16; j++) tmp[j] = WT16[p][uc * 16 + j];
  unsigned short* dst = &Wt[(k * 64 + p) * F + f0 + uc * 16];
  *reinterpret_cast<uint4*>(dst)     = *reinterpret_cast<uint4*>(&tmp[0]);
  *reinterpret_cast<uint4*>(dst + 8) = *reinterpret_cast<uint4*>(&tmp[8]);
}

// ---------------- kernel A: h_bT = Wt·Xb^T via MFMA + fused f1/f2 + fused adj bits -------
__global__ __launch_bounds__(256, 2) void gemm_h(
    const unsigned short* __restrict__ Xb, const unsigned short* __restrict__ Wt,
    const float* __restrict__ a, unsigned short* __restrict__ h_bT,
    float* __restrict__ f1, float* __restrict__ f2,
    const int* __restrict__ adj, unsigned long long* __restrict__ adjb) {
  __shared__ __align__(16) unsigned char AT[2][8192];   // Wt tile [64c][8u][16B]
  __shared__ __align__(16) unsigned char BT[2][8192];   // Xb tile [64n][8u][16B]
  __shared__ float F1L[2][64], F2L[2][64];

  const int t = threadIdx.x;
  const int k = blockIdx.x & 7;
  const int n0 = (blockIdx.x >> 3) * 64;
  const int wave = t >> 6, lane = t & 63;
  const int cg = wave >> 1, ng = wave & 1;
  const int col = lane & 15, kg = lane >> 4;
  const unsigned short* __restrict__ Wk = Wt + (size_t)k * 64 * F;

  f32x4 acc[2][2];
#pragma unroll
  for (int i = 0; i < 2; i++)
#pragma unroll
    for (int j = 0; j < 2; j++) acc[i][j] = (f32x4){0.f, 0.f, 0.f, 0.f};

  auto stage = [&](int tt, int buf) {
    const int f0 = tt * 64;
#pragma unroll
    for (int m = 0; m < 2; m++) {
      const int g = wave * 128 + m * 64 + lane;
      const int row = g >> 3, pu = g & 7;
      const int u = pu ^ (row & 7);
      GLOAD_LDS(Wk + (size_t)row * F + f0 + u * 8,
                AT[buf] + (wave * 128 + m * 64) * 16);
      GLOAD_LDS(Xb + (size_t)(n0 + row) * F + f0 + u * 8,
                BT[buf] + (wave * 128 + m * 64) * 16);
    }
  };

  auto compute = [&](int buf) {
#pragma unroll
    for (int ks = 0; ks < 2; ks++) {
      const int u0 = ks * 4 + kg;
      short8 af[2], bf[2];
#pragma unroll
      for (int i = 0; i < 2; i++) {
        const int rowA = cg * 32 + i * 16 + col;
        af[i] = *reinterpret_cast<const short8*>(
            AT[buf] + (rowA * 8 + (u0 ^ (rowA & 7))) * 16);
        const int rowB = ng * 32 + i * 16 + col;
        bf[i] = *reinterpret_cast<const short8*>(
            BT[buf] + (rowB * 8 + (u0 ^ (rowB & 7))) * 16);
      }
#pragma unroll
      for (int i = 0; i < 2; i++)
#pragma unroll
        for (int j = 0; j < 2; j++)
          acc[i][j] = __builtin_amdgcn_mfma_f32_16x16x32_bf16(af[i], bf[j], acc[i][j], 0, 0, 0);
    }
  };

  // fused adjacency: block owns 512 adjb words; wave owns 128; 16 per K-tile.
  int adjv[16];
  const int wb_wave = blockIdx.x * 512 + wave * 128;
  auto adj_load = [&](int c) {
    const int* p = adj + (size_t)(wb_wave + c * 16) * 64 + lane;
#pragma unroll
    for (int x = 0; x < 16; x++) adjv[x] = p[x * 64];
  };
  auto adj_process = [&](int c) {
    unsigned long long ms[16];
#pragma unroll
    for (int x = 0; x < 16; x++) ms[x] = __ballot(adjv[x] > 0);
    if (lane == 0) {
#pragma unroll
      for (int x = 0; x < 16; x++) adjb[wb_wave + c * 16 + x] = ms[x];
    }
  };

  stage(0, 0);
  adj_load(0);
  for (int tt = 0; tt < F / 64; ++tt) {
    const int cur = tt & 1;
    __builtin_amdgcn_s_barrier();
    __builtin_amdgcn_sched_barrier(0);
    if (tt + 1 < F / 64) {
      stage(tt + 1, 1 - cur);
      asm volatile("s_waitcnt vmcnt(4)" ::: "memory");
    } else {
      asm volatile("s_waitcnt vmcnt(0)" ::: "memory");
    }
    __builtin_amdgcn_s_barrier();
    __builtin_amdgcn_sched_barrier(0);
    if (tt >= 1) {
      adj_process(tt - 1);
      adj_load(tt);
    }
    compute(cur);
  }
  asm volatile("s_waitcnt vmcnt(0)" ::: "memory");
  adj_process(7);

  // ---- epilogue: h_bT bf16 stores + fused f1/f2 (pre-scaled by log2e) ----
  float p1[2] = {0.f, 0.f}, p2[2] = {0.f, 0.f};
#pragma unroll
  for (int i = 0; i < 2; i++) {
#pragma unroll
    for (int r = 0; r < 4; r++) {
      const int p = cg * 32 + i * 16 + kg * 4 + r;
      const float as = a[k * 128 + p];
      const float ad = a[k * 128 + 64 + p];
#pragma unroll
      for (int j = 0; j < 2; j++) {
        const float v = acc[i][j][r];
        h_bT[(size_t)(k * 64 + p) * N + n0 + ng * 32 + j * 16 + col] = f2bs(v);
        p1[j] = fmaf(v, as, p1[j]);
        p2[j] = fmaf(v, ad, p2[j]);
      }
    }
  }
#pragma unroll
  for (int j = 0; j < 2; j++) {
    p1[j] += __shfl_xor(p1[j], 16); p1[j] += __shfl_xor(p1[j], 32);
    p2[j] += __shfl_xor(p2[j], 16); p2[j] += __shfl_xor(p2[j], 32);
    if (kg == 0) {
      F1L[cg][ng * 32 + j * 16 + col] = p1[j];
      F2L[cg][ng * 32 + j * 16 + col] = p2[j];
    }
  }
  __syncthreads();
  if (t < 64) {
    f1[k * N + n0 + t] = (F1L[0][t] + F1L[1][t]) * LOG2E;
    f2[k * N + n0 + t] = (F2L[0][t] + F2L[1][t]) * LOG2E;
  }
}

// ---------------- kernel C: 64-rows-per-wave barrier-free attention ----------------------
// block = 256 thr = 4 waves (4 j-quarters), EACH wave computes all 64 i-rows of the block.
// Per-jg fixed costs (8 h-stage, 8 ds_read, 4 f1 loads, addressing) amortized over
// 4 row-groups. Private 8KB LDS h-slice per wave, single-buffer, self-synced.
__global__ __launch_bounds__(256, 2) void attn_mfma(
    const unsigned short* __restrict__ h_bT, const float* __restrict__ f1,
    const float* __restrict__ f2, const unsigned long long* __restrict__ adjb,
    float* __restrict__ out) {
  __shared__ __align__(16) unsigned char SMEM[32768];   // 4 x 8KB slices; CL aliased at end
  __shared__ float DL[4][64];

  const int tid = threadIdx.x;
  const int k = blockIdx.x & 7;
  const int i0 = (blockIdx.x >> 3) * 64;
  const int jq = tid >> 6, lane = tid & 63;
  const int col = lane & 15, kg = lane >> 4;

  const float* __restrict__ f1k = f1 + k * N;
  const unsigned char* __restrict__ hbb =
      (const unsigned char*)(h_bT + (size_t)k * 64 * N);

  // per-rowgroup f2 (pre-scaled by log2e) as broadcast pairs
  f32x2 f2r2[4];
#pragma unroll
  for (int rg = 0; rg < 4; rg++) {
    const float v = f2[k * N + i0 + rg * 16 + col];
    f2r2[rg] = (f32x2){v, v};
  }
  const f32x2 c02 = {0.2f, 0.2f};

  f32x4 acc[4][4];
  f32x4 accden[4];
#pragma unroll
  for (int rg = 0; rg < 4; rg++) {
    accden[rg] = (f32x4){0.f, 0.f, 0.f, 0.f};
#pragma unroll
    for (int n = 0; n < 4; n++) acc[rg][n] = (f32x4){0.f, 0.f, 0.f, 0.f};
  }
  short8 bones;
#pragma unroll
  for (int e = 0; e < 8; e++) bones[e] = (short)0x3F80;

  unsigned char* MY = SMEM + jq * 8192;     // private slice [64 rows][8 chunks], swz u^(row&7)
  const int jqbase = jq * 1024;

  auto stage = [&](int jg) {
#pragma unroll
    for (int m = 0; m < 8; m++) {
      const int row = m * 8 + (lane >> 3);
      const int phys = lane & 7;
      const int u = phys ^ (row & 7);
      GLOAD_LDS(hbb + (size_t)row * (N * 2) + (jqbase + jg * 64 + u * 8) * 2,
                MY + m * 1024);
    }
  };

  // register prefetch: f1 (4x float4) + adjacency (4x uint2), one jg ahead
  float4 pf[4];
  uint2 pw[4];
  auto pload = [&](int jg) {
    const int jb = jqbase + jg * 64 + kg * 8;
    pf[0] = *reinterpret_cast<const float4*>(&f1k[jb]);
    pf[1] = *reinterpret_cast<const float4*>(&f1k[jb + 4]);
    pf[2] = *reinterpret_cast<const float4*>(&f1k[jb + 32]);
    pf[3] = *reinterpret_cast<const float4*>(&f1k[jb + 36]);
#pragma unroll
    for (int rg = 0; rg < 4; rg++)
      pw[rg] = *reinterpret_cast<const uint2*>(
          adjb + (size_t)(i0 + rg * 16 + col) * 64 + jq * 16 + jg);
  };

  stage(0);
  pload(0);
#pragma unroll 1
  for (int jg = 0; jg < 16; ++jg) {
    // all loads issued last iteration (stage + prefetch) have landed
    asm volatile("s_waitcnt vmcnt(0)" ::: "memory");
    __builtin_amdgcn_sched_barrier(0);

    // ---- score phase: build A-fragments for 4 row-groups x 2 ks (consumes pf/pw) ----
    short8 Af[2][4];
#pragma unroll
    for (int ks = 0; ks < 2; ks++) {
      const f32x2 prs[4] = {{pf[ks * 2].x, pf[ks * 2].y},
                            {pf[ks * 2].z, pf[ks * 2].w},
                            {pf[ks * 2 + 1].x, pf[ks * 2 + 1].y},
                            {pf[ks * 2 + 1].z, pf[ks * 2 + 1].w}};
#pragma unroll
      for (int rg = 0; rg < 4; rg++) {
        const unsigned m = ks ? pw[rg].y : pw[rg].x;
        union { unsigned u[4]; short8 s; } A;
#pragma unroll
        for (int e2 = 0; e2 < 4; e2++) {
          const f32x2 t = pk_add(prs[e2], f2r2[rg]);
          const f32x2 u = pk_mul(t, c02);
          float wa = exp2_asm(fmaxf(t.x, u.x));
          float wb = exp2_asm(fmaxf(t.y, u.y));
          const int ob = kg * 8 + 2 * e2;
          wa = mask_w(wa, m, ob);
          wb = mask_w(wb, m, ob + 1);
          asm("v_cvt_pk_bf16_f32 %0, %1, %2" : "=v"(A.u[e2]) : "v"(wa), "v"(wb));
        }
        Af[ks][rg] = A.s;
      }
    }

    // ---- h fragments from private LDS (staged one jg ago) ----
    short8 bfr[2][4];
#pragma unroll
    for (int ks = 0; ks < 2; ks++)
#pragma unroll
      for (int n = 0; n < 4; n++) {
        const int row_b = n * 16 + col;
        const int u = ks * 4 + kg;
        bfr[ks][n] = *reinterpret_cast<const short8*>(
            MY + row_b * 128 + (u ^ (row_b & 7)) * 16);
      }
    asm volatile("s_waitcnt lgkmcnt(0)" ::: "memory");
    __builtin_amdgcn_sched_barrier(0);

    // ---- issue next tile's loads; they retire under the MFMA + next score phase ----
    if (jg + 1 < 16) {
      stage(jg + 1);
      pload(jg + 1);
    }

    // ---- MFMA: 4 row-groups x (1 den + 4 n) x 2 ks ----
    __builtin_amdgcn_s_setprio(1);
#pragma unroll
    for (int ks = 0; ks < 2; ks++)
#pragma unroll
      for (int rg = 0; rg < 4; rg++) {
        accden[rg] = __builtin_amdgcn_mfma_f32_16x16x32_bf16(Af[ks][rg], bones, accden[rg], 0, 0, 0);
#pragma unroll
        for (int n = 0; n < 4; n++)
          acc[rg][n] = __builtin_amdgcn_mfma_f32_16x16x32_bf16(Af[ks][rg], bfr[ks][n], acc[rg][n], 0, 0, 0);
      }
    __builtin_amdgcn_s_setprio(0);
  }

  __syncthreads();                          // all waves done; SMEM reusable as CL

  // ---- denominators ----
  if (col == 0) {
#pragma unroll
    for (int rg = 0; rg < 4; rg++)
#pragma unroll
      for (int r = 0; r < 4; r++) DL[jq][rg * 16 + kg * 4 + r] = accden[rg][r];
  }

  // ---- two-pass cross-jq reduction (CL = 3x64x33 floats = 25.3KB in SMEM) ----
  float* CL = (float*)SMEM;
  float rinv[4][4];
#pragma unroll
  for (int h = 0; h < 2; ++h) {
    if (jq != 0) {
#pragma unroll
      for (int rg = 0; rg < 4; rg++)
#pragma unroll
        for (int nn = 0; nn < 2; nn++)
#pragma unroll
          for (int r = 0; r < 4; r++)
            CL[((jq - 1) * 64 + rg * 16 + kg * 4 + r) * 33 + nn * 16 + col] =
                acc[rg][h * 2 + nn][r];
    }
    __syncthreads();
    if (jq == 0) {
      if (h == 0) {
#pragma unroll
        for (int rg = 0; rg < 4; rg++)
#pragma unroll
          for (int r = 0; r < 4; r++) {
            const int il = rg * 16 + kg * 4 + r;
            rinv[rg][r] = 1.f / (DL[0][il] + DL[1][il] + DL[2][il] + DL[3][il]);
          }
      }
#pragma unroll
      for (int rg = 0; rg < 4; rg++)
#pragma unroll
        for (int r = 0; r < 4; r++) {
          const int il = rg * 16 + kg * 4 + r;
#pragma unroll
          for (int nn = 0; nn < 2; nn++) {
            const int n = h * 2 + nn;
            float v = acc[rg][n][r];
            v += CL[(0 * 64 + il) * 33 + nn * 16 + col];
            v += CL[(1 * 64 + il) * 33 + nn * 16 + col];
            v += CL[(2 * 64 + il) * 33 + nn * 16 + col];
            out[(size_t)(i0 + il) * KFP + k * 64 + n * 16 + col] = v * rinv[rg][r];
          }
        }
    }
    __syncthreads();
  }
}

// ---------------- launch ----------------------------------------------------------------
extern "C" void kernel_launch(void* const* d_in, const int* in_sizes, int n_in,
                              void* d_out, int out_size, void* d_ws, size_t ws_size,
                              hipStream_t stream) {
  const float* X   = (const float*)d_in[0];             // (N, F)
  const int*   adj = (const int*)d_in[1];               // (N, N)
  const float* W   = (const float*)d_in[2];             // (K, F, FP)
  const float* a   = (const float*)d_in[3];             // (K, 2*FP, 1)
  float* out = (float*)d_out;                           // (N, K*FP) = 8 MB

  char* ws = (char*)d_ws;
  unsigned short* h_bT = (unsigned short*)(ws);                    // 4 MB
  float* f1  = (float*)(ws + 4194304);                             // 128 KB
  float* f2  = (float*)(ws + 4325376);                             // 128 KB
  unsigned long long* adjb = (unsigned long long*)(ws + 4456448);  // 2 MB
  unsigned short* Wt = (unsigned short*)(ws + 6553600);            // 512 KB
  // Xb parked in d_out (4 MB of its 8 MB) — consumed by gemm_h before attn overwrites out
  unsigned short* Xb = (unsigned short*)d_out;

  hipLaunchKernelGGL(prep_fused, dim3(1024 + K * (F / 64)), dim3(256), 0, stream,
                     X, Xb, W, Wt);
  hipLaunchKernelGGL(gemm_h, dim3(K * (N / 64)), dim3(256), 0, stream,
                     Xb, Wt, a, h_bT, f1, f2, adj, adjb);
  hipLaunchKernelGGL(attn_mfma, dim3((N / 64) * K), dim3(256), 0, stream,
                     h_bT, f1, f2, adjb, out);
}

// Round 14
// 76.663 us; speedup vs baseline: 1.4512x; 1.0361x over previous
//
#include <hip/hip_runtime.h>
#include <hip/hip_bf16.h>

#define N 4096
#define F 512
#define FP 64
#define K 8
#define KFP 512          // K*FP
#define LOG2E 1.44269504088896f

typedef __attribute__((ext_vector_type(8))) short short8;
typedef __attribute__((ext_vector_type(4))) float f32x4;

__device__ __forceinline__ unsigned short f2bs(float x) {
  union { __bf16 b; unsigned short u; } u;
  u.b = (__bf16)x;
  return u.u;
}

// masked = bit(off) of mb ? w : 0.0f   (sbfe-sext + and, both via builtins/plain C)
__device__ __forceinline__ float mask_w(float w, unsigned mb, int off) {
  return __int_as_float(__float_as_int(w) & __builtin_amdgcn_sbfe((int)mb, off, 1));
}

#define GLOAD_LDS(src, dst) \
  __builtin_amdgcn_global_load_lds( \
      (const __attribute__((address_space(1))) void*)(src), \
      (__attribute__((address_space(3))) void*)(dst), 16, 0, 0)

// ---------------- prep: Xb = bf16(X), Wt = bf16(W transposed) ----------------------------
__global__ __launch_bounds__(256) void prep_fused(const float* __restrict__ X,
                                                  unsigned short* __restrict__ Xb,
                                                  const float* __restrict__ W,
                                                  unsigned short* __restrict__ Wt) {
  __shared__ unsigned short WT16[64][66];
  const int t = threadIdx.x;
  if (blockIdx.x < 1024) {                  // X -> Xb, 8 elems/thread
    const int idx = (blockIdx.x * 256 + t) * 8;
    const float4 v0 = *reinterpret_cast<const float4*>(&X[idx]);
    const float4 v1 = *reinterpret_cast<const float4*>(&X[idx + 4]);
    unsigned short o[8] = {f2bs(v0.x), f2bs(v0.y), f2bs(v0.z), f2bs(v0.w),
                           f2bs(v1.x), f2bs(v1.y), f2bs(v1.z), f2bs(v1.w)};
    *reinterpret_cast<uint4*>(&Xb[idx]) = *reinterpret_cast<uint4*>(&o[0]);
    return;
  }
  const int bid = blockIdx.x - 1024;        // W[K][F][FP] -> Wt[K*FP][F]
  const int k = bid >> 3;
  const int f0 = (bid & 7) * 64;
#pragma unroll
  for (int j = 0; j < 16; j++) {
    const int idx = j * 256 + t;
    const int fl = idx >> 6, p = idx & 63;
    WT16[p][fl] = f2bs(W[(k * F + f0 + fl) * FP + p]);
  }
  __syncthreads();
  const int p = t >> 2, uc = t & 3;
  unsigned short tmp[16];
#pragma unroll
  for (int j = 0; j < 16; j++) tmp[j] = WT16[p][uc * 16 + j];
  unsigned short* dst = &Wt[(k * 64 + p) * F + f0 + uc * 16];
  *reinterpret_cast<uint4*>(dst)     = *reinterpret_cast<uint4*>(&tmp[0]);
  *reinterpret_cast<uint4*>(dst + 8) = *reinterpret_cast<uint4*>(&tmp[8]);
}

// ---------------- kernel A: h_bT = Wt·Xb^T via MFMA + fused f1/f2 + fused adj bits -------
__global__ __launch_bounds__(256, 2) void gemm_h(
    const unsigned short* __restrict__ Xb, const unsigned short* __restrict__ Wt,
    const float* __restrict__ a, unsigned short* __restrict__ h_bT,
    float* __restrict__ f1, float* __restrict__ f2,
    const int* __restrict__ adj, unsigned long long* __restrict__ adjb) {
  __shared__ __align__(16) unsigned char AT[2][8192];   // Wt tile [64c][8u][16B]
  __shared__ __align__(16) unsigned char BT[2][8192];   // Xb tile [64n][8u][16B]
  __shared__ float F1L[2][64], F2L[2][64];

  const int t = threadIdx.x;
  const int k = blockIdx.x & 7;
  const int n0 = (blockIdx.x >> 3) * 64;
  const int wave = t >> 6, lane = t & 63;
  const int cg = wave >> 1, ng = wave & 1;
  const int col = lane & 15, kg = lane >> 4;
  const unsigned short* __restrict__ Wk = Wt + (size_t)k * 64 * F;

  f32x4 acc[2][2];
#pragma unroll
  for (int i = 0; i < 2; i++)
#pragma unroll
    for (int j = 0; j < 2; j++) acc[i][j] = (f32x4){0.f, 0.f, 0.f, 0.f};

  auto stage = [&](int tt, int buf) {
    const int f0 = tt * 64;
#pragma unroll
    for (int m = 0; m < 2; m++) {
      const int g = wave * 128 + m * 64 + lane;
      const int row = g >> 3, pu = g & 7;
      const int u = pu ^ (row & 7);
      GLOAD_LDS(Wk + (size_t)row * F + f0 + u * 8,
                AT[buf] + (wave * 128 + m * 64) * 16);
      GLOAD_LDS(Xb + (size_t)(n0 + row) * F + f0 + u * 8,
                BT[buf] + (wave * 128 + m * 64) * 16);
    }
  };

  auto compute = [&](int buf) {
#pragma unroll
    for (int ks = 0; ks < 2; ks++) {
      const int u0 = ks * 4 + kg;
      short8 af[2], bf[2];
#pragma unroll
      for (int i = 0; i < 2; i++) {
        const int rowA = cg * 32 + i * 16 + col;
        af[i] = *reinterpret_cast<const short8*>(
            AT[buf] + (rowA * 8 + (u0 ^ (rowA & 7))) * 16);
        const int rowB = ng * 32 + i * 16 + col;
        bf[i] = *reinterpret_cast<const short8*>(
            BT[buf] + (rowB * 8 + (u0 ^ (rowB & 7))) * 16);
      }
#pragma unroll
      for (int i = 0; i < 2; i++)
#pragma unroll
        for (int j = 0; j < 2; j++)
          acc[i][j] = __builtin_amdgcn_mfma_f32_16x16x32_bf16(af[i], bf[j], acc[i][j], 0, 0, 0);
    }
  };

  // fused adjacency: block owns 512 adjb words; wave owns 128; 16 per K-tile.
  int adjv[16];
  const int wb_wave = blockIdx.x * 512 + wave * 128;
  auto adj_load = [&](int c) {
    const int* p = adj + (size_t)(wb_wave + c * 16) * 64 + lane;
#pragma unroll
    for (int x = 0; x < 16; x++) adjv[x] = p[x * 64];
  };
  auto adj_process = [&](int c) {
    unsigned long long ms[16];
#pragma unroll
    for (int x = 0; x < 16; x++) ms[x] = __ballot(adjv[x] > 0);
    if (lane == 0) {
#pragma unroll
      for (int x = 0; x < 16; x++) adjb[wb_wave + c * 16 + x] = ms[x];
    }
  };

  stage(0, 0);
  adj_load(0);
  for (int tt = 0; tt < F / 64; ++tt) {
    const int cur = tt & 1;
    __builtin_amdgcn_s_barrier();
    __builtin_amdgcn_sched_barrier(0);
    if (tt + 1 < F / 64) {
      stage(tt + 1, 1 - cur);
      asm volatile("s_waitcnt vmcnt(4)" ::: "memory");
    } else {
      asm volatile("s_waitcnt vmcnt(0)" ::: "memory");
    }
    __builtin_amdgcn_s_barrier();
    __builtin_amdgcn_sched_barrier(0);
    if (tt >= 1) {
      adj_process(tt - 1);
      adj_load(tt);
    }
    compute(cur);
  }
  asm volatile("s_waitcnt vmcnt(0)" ::: "memory");
  adj_process(7);

  // ---- epilogue: h_bT bf16 stores + fused f1/f2 (pre-scaled by log2e) ----
  float p1[2] = {0.f, 0.f}, p2[2] = {0.f, 0.f};
#pragma unroll
  for (int i = 0; i < 2; i++) {
#pragma unroll
    for (int r = 0; r < 4; r++) {
      const int p = cg * 32 + i * 16 + kg * 4 + r;
      const float as = a[k * 128 + p];
      const float ad = a[k * 128 + 64 + p];
#pragma unroll
      for (int j = 0; j < 2; j++) {
        const float v = acc[i][j][r];
        h_bT[(size_t)(k * 64 + p) * N + n0 + ng * 32 + j * 16 + col] = f2bs(v);
        p1[j] = fmaf(v, as, p1[j]);
        p2[j] = fmaf(v, ad, p2[j]);
      }
    }
  }
#pragma unroll
  for (int j = 0; j < 2; j++) {
    p1[j] += __shfl_xor(p1[j], 16); p1[j] += __shfl_xor(p1[j], 32);
    p2[j] += __shfl_xor(p2[j], 16); p2[j] += __shfl_xor(p2[j], 32);
    if (kg == 0) {
      F1L[cg][ng * 32 + j * 16 + col] = p1[j];
      F2L[cg][ng * 32 + j * 16 + col] = p2[j];
    }
  }
  __syncthreads();
  if (t < 64) {
    f1[k * N + n0 + t] = (F1L[0][t] + F1L[1][t]) * LOG2E;
    f2[k * N + n0 + t] = (F2L[0][t] + F2L[1][t]) * LOG2E;
  }
}

// ---------------- kernel C: 64-rows-per-wave attention, PLAIN-HIP score path -------------
// Same structure as R12 (4 waves = 4 j-quarters, private 8KB LDS h-slice, self-synced),
// but the score phase is plain HIP — no pk asm, no cvt_pk asm — so the compiler
// schedules/vectorizes it (m240: hand-asm cvt_pk was -37% vs scalar-cast path).
__global__ __launch_bounds__(256, 2) void attn_mfma(
    const unsigned short* __restrict__ h_bT, const float* __restrict__ f1,
    const float* __restrict__ f2, const unsigned long long* __restrict__ adjb,
    float* __restrict__ out) {
  __shared__ __align__(16) unsigned char SMEM[32768];   // 4 x 8KB slices; CL aliased at end
  __shared__ float DL[4][64];

  const int tid = threadIdx.x;
  const int k = blockIdx.x & 7;
  const int i0 = (blockIdx.x >> 3) * 64;
  const int jq = tid >> 6, lane = tid & 63;
  const int col = lane & 15, kg = lane >> 4;

  const float* __restrict__ f1k = f1 + k * N;
  const unsigned char* __restrict__ hbb =
      (const unsigned char*)(h_bT + (size_t)k * 64 * N);

  float f2r[4];
#pragma unroll
  for (int rg = 0; rg < 4; rg++) f2r[rg] = f2[k * N + i0 + rg * 16 + col];

  f32x4 acc[4][4];
  f32x4 accden[4];
#pragma unroll
  for (int rg = 0; rg < 4; rg++) {
    accden[rg] = (f32x4){0.f, 0.f, 0.f, 0.f};
#pragma unroll
    for (int n = 0; n < 4; n++) acc[rg][n] = (f32x4){0.f, 0.f, 0.f, 0.f};
  }
  short8 bones;
#pragma unroll
  for (int e = 0; e < 8; e++) bones[e] = (short)0x3F80;

  unsigned char* MY = SMEM + jq * 8192;     // private slice [64 rows][8 chunks], swz u^(row&7)
  const int jqbase = jq * 1024;

  auto stage = [&](int jg) {
#pragma unroll
    for (int m = 0; m < 8; m++) {
      const int row = m * 8 + (lane >> 3);
      const int phys = lane & 7;
      const int u = phys ^ (row & 7);
      GLOAD_LDS(hbb + (size_t)row * (N * 2) + (jqbase + jg * 64 + u * 8) * 2,
                MY + m * 1024);
    }
  };

  // register prefetch: f1 (4x float4) + adjacency (4x uint2), one jg ahead
  float4 pf[4];
  uint2 pw[4];
  auto pload = [&](int jg) {
    const int jb = jqbase + jg * 64 + kg * 8;
    pf[0] = *reinterpret_cast<const float4*>(&f1k[jb]);
    pf[1] = *reinterpret_cast<const float4*>(&f1k[jb + 4]);
    pf[2] = *reinterpret_cast<const float4*>(&f1k[jb + 32]);
    pf[3] = *reinterpret_cast<const float4*>(&f1k[jb + 36]);
#pragma unroll
    for (int rg = 0; rg < 4; rg++)
      pw[rg] = *reinterpret_cast<const uint2*>(
          adjb + (size_t)(i0 + rg * 16 + col) * 64 + jq * 16 + jg);
  };

  stage(0);
  pload(0);
#pragma unroll 1
  for (int jg = 0; jg < 16; ++jg) {
    // stage(jg) + pload(jg) issued one iteration ago — drained here
    asm volatile("s_waitcnt vmcnt(0)" ::: "memory");
    __builtin_amdgcn_sched_barrier(0);

    // ---- h fragments from private LDS (plain reads; compiler manages lgkm) ----
    short8 bfr[2][4];
#pragma unroll
    for (int ks = 0; ks < 2; ks++)
#pragma unroll
      for (int n = 0; n < 4; n++) {
        const int row_b = n * 16 + col;
        const int u = ks * 4 + kg;
        bfr[ks][n] = *reinterpret_cast<const short8*>(
            MY + row_b * 128 + (u ^ (row_b & 7)) * 16);
      }

    // ---- score phase: PLAIN HIP, compiler-scheduled ----
    short8 Af[2][4];
#pragma unroll
    for (int ks = 0; ks < 2; ks++) {
      const float fv[8] = {pf[ks * 2].x, pf[ks * 2].y, pf[ks * 2].z, pf[ks * 2].w,
                           pf[ks * 2 + 1].x, pf[ks * 2 + 1].y,
                           pf[ks * 2 + 1].z, pf[ks * 2 + 1].w};
#pragma unroll
      for (int rg = 0; rg < 4; rg++) {
        const unsigned m = ks ? pw[rg].y : pw[rg].x;
        const float fr = f2r[rg];
        float w[8];
#pragma unroll
        for (int e = 0; e < 8; e++) {
          const float s0 = fr + fv[e];
          const float s = fmaxf(s0, 0.2f * s0);
          w[e] = mask_w(__builtin_amdgcn_exp2f(s), m, kg * 8 + e);
        }
        union { unsigned u[4]; short8 s; } A;
#pragma unroll
        for (int e2 = 0; e2 < 4; e2++)
          A.u[e2] = (unsigned)f2bs(w[2 * e2]) | ((unsigned)f2bs(w[2 * e2 + 1]) << 16);
        Af[ks][rg] = A.s;
      }
    }

    // all prior LDS reads retired before restaging into the same slice
    asm volatile("s_waitcnt lgkmcnt(0)" ::: "memory");
    __builtin_amdgcn_sched_barrier(0);
    if (jg + 1 < 16) {
      stage(jg + 1);
      pload(jg + 1);
    }

    // ---- MFMA: 4 row-groups x (1 den + 4 n) x 2 ks ----
    __builtin_amdgcn_s_setprio(1);
#pragma unroll
    for (int ks = 0; ks < 2; ks++)
#pragma unroll
      for (int rg = 0; rg < 4; rg++) {
        accden[rg] = __builtin_amdgcn_mfma_f32_16x16x32_bf16(Af[ks][rg], bones, accden[rg], 0, 0, 0);
#pragma unroll
        for (int n = 0; n < 4; n++)
          acc[rg][n] = __builtin_amdgcn_mfma_f32_16x16x32_bf16(Af[ks][rg], bfr[ks][n], acc[rg][n], 0, 0, 0);
      }
    __builtin_amdgcn_s_setprio(0);
  }

  __syncthreads();                          // all waves done; SMEM reusable as CL

  // ---- denominators ----
  if (col == 0) {
#pragma unroll
    for (int rg = 0; rg < 4; rg++)
#pragma unroll
      for (int r = 0; r < 4; r++) DL[jq][rg * 16 + kg * 4 + r] = accden[rg][r];
  }

  // ---- two-pass cross-jq reduction (CL = 3x64x33 floats = 25.3KB in SMEM) ----
  float* CL = (float*)SMEM;
  float rinv[4][4];
#pragma unroll
  for (int h = 0; h < 2; ++h) {
    if (jq != 0) {
#pragma unroll
      for (int rg = 0; rg < 4; rg++)
#pragma unroll
        for (int nn = 0; nn < 2; nn++)
#pragma unroll
          for (int r = 0; r < 4; r++)
            CL[((jq - 1) * 64 + rg * 16 + kg * 4 + r) * 33 + nn * 16 + col] =
                acc[rg][h * 2 + nn][r];
    }
    __syncthreads();
    if (jq == 0) {
      if (h == 0) {
#pragma unroll
        for (int rg = 0; rg < 4; rg++)
#pragma unroll
          for (int r = 0; r < 4; r++) {
            const int il = rg * 16 + kg * 4 + r;
            rinv[rg][r] = 1.f / (DL[0][il] + DL[1][il] + DL[2][il] + DL[3][il]);
          }
      }
#pragma unroll
      for (int rg = 0; rg < 4; rg++)
#pragma unroll
        for (int r = 0; r < 4; r++) {
          const int il = rg * 16 + kg * 4 + r;
#pragma unroll
          for (int nn = 0; nn < 2; nn++) {
            const int n = h * 2 + nn;
            float v = acc[rg][n][r];
            v += CL[(0 * 64 + il) * 33 + nn * 16 + col];
            v += CL[(1 * 64 + il) * 33 + nn * 16 + col];
            v += CL[(2 * 64 + il) * 33 + nn * 16 + col];
            out[(size_t)(i0 + il) * KFP + k * 64 + n * 16 + col] = v * rinv[rg][r];
          }
        }
    }
    __syncthreads();
  }
}

// ---------------- launch ----------------------------------------------------------------
extern "C" void kernel_launch(void* const* d_in, const int* in_sizes, int n_in,
                              void* d_out, int out_size, void* d_ws, size_t ws_size,
                              hipStream_t stream) {
  const float* X   = (const float*)d_in[0];             // (N, F)
  const int*   adj = (const int*)d_in[1];               // (N, N)
  const float* W   = (const float*)d_in[2];             // (K, F, FP)
  const float* a   = (const float*)d_in[3];             // (K, 2*FP, 1)
  float* out = (float*)d_out;                           // (N, K*FP) = 8 MB

  char* ws = (char*)d_ws;
  unsigned short* h_bT = (unsigned short*)(ws);                    // 4 MB
  float* f1  = (float*)(ws + 4194304);                             // 128 KB
  float* f2  = (float*)(ws + 4325376);                             // 128 KB
  unsigned long long* adjb = (unsigned long long*)(ws + 4456448);  // 2 MB
  unsigned short* Wt = (unsigned short*)(ws + 6553600);            // 512 KB
  // Xb parked in d_out (4 MB of its 8 MB) — consumed by gemm_h before attn overwrites out
  unsigned short* Xb = (unsigned short*)d_out;

  hipLaunchKernelGGL(prep_fused, dim3(1024 + K * (F / 64)), dim3(256), 0, stream,
                     X, Xb, W, Wt);
  hipLaunchKernelGGL(gemm_h, dim3(K * (N / 64)), dim3(256), 0, stream,
                     Xb, Wt, a, h_bT, f1, f2, adj, adjb);
  hipLaunchKernelGGL(attn_mfma, dim3((N / 64) * K), dim3(256), 0, stream,
                     h_bT, f1, f2, adjb, out);
}